// Round 11
// baseline (179.496 us; speedup 1.0000x reference)
//
#include <hip/hip_runtime.h>
#include <hip/hip_bf16.h>
#include <math.h>

#define NEGV (-1e10f)

typedef __attribute__((ext_vector_type(8))) short bf16x8;
typedef __attribute__((ext_vector_type(4))) float f32x4;
typedef __attribute__((ext_vector_type(16))) float f32x16;

static __device__ __forceinline__ unsigned short f2bf(float f) {
  unsigned int u = __builtin_bit_cast(unsigned int, f);
  unsigned int r = (u + 0x7fffu + ((u >> 16) & 1u)) >> 16;
  return (unsigned short)r;
}
static __device__ __forceinline__ float bf2f(unsigned short v) {
  return __builtin_bit_cast(float, (unsigned int)v << 16);
}

// ---------------------------------------------------------------------------
// 16x16x32-fragment layout used for GEMM A and B operands:
//   element (row, k) lives at chunk = (row/16)*24 + k/32  (1KB chunks),
//   in-chunk lane = (row%16) + 16*((k/8)%4), elem = k%8.
// One MFMA operand = one chunk = lane-linear 16B/lane -> single coalesced
// global_load_dwordx4, no LDS needed.
// ---------------------------------------------------------------------------

// ---------------------------------------------------------------------------
// K1: casts into fragment layouts. Blocks [0,2048): emb -> Af (fragment) +
// logits (LDS-atomic row reduction). Blocks [2048,2624): W -> Wf (fragment).
// W_q/W_k use the R9 row-permutation orow(f) (same perm on Q and K -> QK^T
// invariant) composed into the fragment placement; W_v uses identity.
// Block = 384 threads; thread owns one 16B segment (8 consecutive k).
// ---------------------------------------------------------------------------
__global__ __launch_bounds__(384) void cast_inputs(
    const float* __restrict__ emb, const int* __restrict__ tags,
    const float* __restrict__ ww, const float* __restrict__ wq,
    const float* __restrict__ wk, const float* __restrict__ wv,
    unsigned short* __restrict__ Af, float* __restrict__ logits,
    unsigned short* __restrict__ Wf) {
  __shared__ float lred[4];
  int bx = blockIdx.x, t = threadIdx.x;
  if (bx < 2048) {
    int row = bx * 4 + t / 96;
    int seg = t % 96, k0 = seg * 8;
    if (t < 4) lred[t] = 0.f;
    __syncthreads();
    const float4* p = (const float4*)(emb + (size_t)row * 768 + k0);
    const float4* wp = (const float4*)(ww + k0);
    float4 v0 = p[0], v1 = p[1];
    float4 w0 = wp[0], w1 = wp[1];
    float d = v0.x * w0.x + v0.y * w0.y + v0.z * w0.z + v0.w * w0.w +
              v1.x * w1.x + v1.y * w1.y + v1.z * w1.z + v1.w * w1.w;
    atomicAdd(&lred[t / 96], d);
    // fragment store: 8 elems = one 16B write
    int chunk = (row >> 4) * 24 + (k0 >> 5);
    int lane32 = (row & 15) + 16 * ((k0 >> 3) & 3);
    ushort4 o0, o1;
    o0.x = f2bf(v0.x); o0.y = f2bf(v0.y); o0.z = f2bf(v0.z); o0.w = f2bf(v0.w);
    o1.x = f2bf(v1.x); o1.y = f2bf(v1.y); o1.z = f2bf(v1.z); o1.w = f2bf(v1.w);
    ushort4* dst = (ushort4*)(Af + (size_t)chunk * 512 + lane32 * 8);
    dst[0] = o0;
    dst[1] = o1;
    __syncthreads();
    if (t < 4) {
      int r = bx * 4 + t;
      logits[r] = (tags[r] == 0) ? NEGV : lred[t];
    }
  } else {
    int g = (bx - 2048) * 384 + t;  // 0..221183
    int z = g / 73728;
    int rem = g - z * 73728;
    int f = rem / 96, seg = rem % 96, k0 = seg * 8;
    const float* src = (z == 0) ? wq : (z == 1) ? wk : wv;
    const float4* p = (const float4*)(src + (size_t)f * 768 + k0);
    float4 v0 = p[0], v1 = p[1];
    int orow;
    if (z == 2) {
      orow = f;
    } else {
      int h = f & 7, dg = f >> 3;       // head, depth 0..95
      int tt = dg >> 4, ddl = dg & 15;
      int wn = ddl >> 3, cb = (ddl >> 2) & 1, j = ddl & 3;
      orow = tt * 128 + wn * 64 + j * 16 + cb * 8 + h;
    }
    int chunk = (orow >> 4) * 24 + (k0 >> 5);
    int lane32 = (orow & 15) + 16 * ((k0 >> 3) & 3);
    ushort4 o0, o1;
    o0.x = f2bf(v0.x); o0.y = f2bf(v0.y); o0.z = f2bf(v0.z); o0.w = f2bf(v0.w);
    o1.x = f2bf(v1.x); o1.y = f2bf(v1.y); o1.z = f2bf(v1.z); o1.w = f2bf(v1.w);
    ushort4* dst =
        (ushort4*)(Wf + (size_t)z * 589824 + (size_t)chunk * 512 + lane32 * 8);
    dst[0] = o0;
    dst[1] = o1;
  }
}

// ---------------------------------------------------------------------------
// K2: softmax over s=1024 per batch of the masked logits -> aw
// ---------------------------------------------------------------------------
__global__ __launch_bounds__(256) void softmax_aw(
    const float* __restrict__ logits, float* __restrict__ aw) {
  __shared__ float red[4];
  int b = blockIdx.x, t = threadIdx.x;
  const float* L = logits + b * 1024;
  float x0 = L[t], x1 = L[t + 256], x2 = L[t + 512], x3 = L[t + 768];
  float m = fmaxf(fmaxf(x0, x1), fmaxf(x2, x3));
#pragma unroll
  for (int off = 32; off; off >>= 1) m = fmaxf(m, __shfl_xor(m, off));
  if ((t & 63) == 0) red[t >> 6] = m;
  __syncthreads();
  m = fmaxf(fmaxf(red[0], red[1]), fmaxf(red[2], red[3]));
  float e0 = __expf(x0 - m), e1 = __expf(x1 - m), e2 = __expf(x2 - m),
        e3 = __expf(x3 - m);
  float s = e0 + e1 + e2 + e3;
#pragma unroll
  for (int off = 32; off; off >>= 1) s += __shfl_xor(s, off);
  __syncthreads();
  if ((t & 63) == 0) red[t >> 6] = s;
  __syncthreads();
  float inv = 1.0f / (red[0] + red[1] + red[2] + red[3]);
  float* A = aw + b * 1024;
  A[t] = e0 * inv; A[t + 256] = e1 * inv;
  A[t + 512] = e2 * inv; A[t + 768] = e3 * inv;
}

// ---------------------------------------------------------------------------
// K3: QKV projection GEMM, BARRIER-FREE K-loop. 128x128 tile, 4 waves of
// 64x64 (4x4 16x16x32 MFMA). A and B operands read directly global->VGPR as
// 1KB fragment chunks (layouts written by K1) — no LDS staging, no
// __syncthreads in the loop; compiler pipelines loads via vmcnt.
// LDS used only for the epilogue repack (unchanged from R10).
// z=0 -> Q (32x32-attn-fragment layout), z=1 -> K same, z=2 -> V row-major.
// ---------------------------------------------------------------------------
__global__ __launch_bounds__(256) void qkv_gemm(
    const unsigned short* __restrict__ Af, const unsigned short* __restrict__ Wf,
    unsigned short* __restrict__ Qf, unsigned short* __restrict__ Kf,
    unsigned short* __restrict__ Vbf) {
  __shared__ __align__(16) unsigned short sm[17408];  // epilogue repack only
  int z = blockIdx.z;
  int mb = blockIdx.x * 128, nb = blockIdx.y * 128;
  int tid = threadIdx.x;
  int w = tid >> 6, lane = tid & 63;
  int wm = w >> 1, wn = w & 1;
  int c = lane & 15, quad = lane >> 4;
  // operand bases: chunk(tile, it)*512 + lane*8
  const unsigned short* Ab =
      Af + ((size_t)((mb >> 4) + wm * 4) * 24) * 512 + (size_t)lane * 8;
  const unsigned short* Bb = Wf + (size_t)z * 589824 +
                             ((size_t)((nb >> 4) + wn * 4) * 24) * 512 +
                             (size_t)lane * 8;

  f32x4 acc[4][4];
#pragma unroll
  for (int i = 0; i < 4; i++)
#pragma unroll
    for (int j = 0; j < 4; j++) acc[i][j] = 0;

#pragma unroll 4
  for (int it = 0; it < 24; it++) {
    bf16x8 af[4], bfr[4];
#pragma unroll
    for (int i = 0; i < 4; i++)
      af[i] = *(const bf16x8*)(Ab + (size_t)(i * 24 + it) * 512);
#pragma unroll
    for (int j = 0; j < 4; j++)
      bfr[j] = *(const bf16x8*)(Bb + (size_t)(j * 24 + it) * 512);
#pragma unroll
    for (int i = 0; i < 4; i++)
#pragma unroll
      for (int j = 0; j < 4; j++)
        acc[i][j] = __builtin_amdgcn_mfma_f32_16x16x32_bf16(af[i], bfr[j],
                                                            acc[i][j], 0, 0, 0);
  }

  // C row = mb+wm*64+i*16+quad*4+r, col = nb+wn*64+j*16+c  (col = stored orow)
  if (z == 2) {
#pragma unroll
    for (int i = 0; i < 4; i++)
#pragma unroll
      for (int j = 0; j < 4; j++)
#pragma unroll
        for (int r = 0; r < 4; r++) {
          int rl = wm * 64 + i * 16 + quad * 4 + r;
          int cl = wn * 64 + j * 16 + c;
          sm[rl * 136 + cl] = f2bf(acc[i][j][r]);
        }
    __syncthreads();
#pragma unroll
    for (int it2 = 0; it2 < 8; it2++) {
      int g2 = it2 * 256 + tid;  // 0..2047, 16B units (128 rows x 16)
      int rl = g2 >> 4;
      int cu = (g2 & 15) * 8;
      bf16x8 vdat = *(const bf16x8*)&sm[rl * 136 + cu];
      *(bf16x8*)&Vbf[(size_t)(mb + rl) * 768 + nb + cu] = vdat;
    }
  } else {
    unsigned short* O = (z == 0) ? Qf : Kf;
    // stored-row o: h = c&7, elem = 4*(c>>3)+j (R9 perm) -> b64 LDS writes
#pragma unroll
    for (int i = 0; i < 4; i++) {
#pragma unroll
      for (int r = 0; r < 4; r++) {
        int qlr = wm * 64 + i * 16 + quad * 4 + r;  // 0..127
        int chunkL = (qlr >> 5) * 8 + (c & 7);      // 0..31
        int lane32 = (qlr & 31) + wn * 32;
        ushort4 pk;
        pk.x = f2bf(acc[i][0][r]);
        pk.y = f2bf(acc[i][1][r]);
        pk.z = f2bf(acc[i][2][r]);
        pk.w = f2bf(acc[i][3][r]);
        *(ushort4*)&sm[chunkL * 520 + lane32 * 8 + 4 * (c >> 3)] = pk;
      }
    }
    __syncthreads();
    int bq = mb >> 10;
    int qt32g0 = (mb & 1023) >> 5;
    int tt = blockIdx.y;  // d/16 chunk (0..5)
#pragma unroll
    for (int it2 = 0; it2 < 8; it2++) {
      int g = it2 * 256 + tid;
      int chunkL = g >> 6;
      int off = (g & 63) * 8;
      bf16x8 vdat = *(const bf16x8*)&sm[chunkL * 520 + off];
      int qt32 = qt32g0 + (chunkL >> 3), h = chunkL & 7;
      size_t dst = ((((size_t)(bq * 32 + qt32) * 8 + h) * 6 + tt) << 9) + off;
      *(bf16x8*)&O[dst] = vdat;
    }
  }
}

// ---------------------------------------------------------------------------
// K4: attention (R10 version, kept). Block = 64q x 64k x 8h, 4 waves
// (2x2 of 32x32 via mfma_f32_32x32x16_bf16), barrier-free direct global->VGPR
// fragment loads, h-softmax without max-shift, XCD batch pinning.
// ---------------------------------------------------------------------------
__global__ __launch_bounds__(256) void attn(
    const unsigned short* __restrict__ Qf, const unsigned short* __restrict__ Kf,
    const float* __restrict__ aw, float* __restrict__ Ptp) {
  __shared__ float pbuf[1024];  // (wq*2+wk)*256 + kcol*8 + h
  int id = blockIdx.x;
  int b = id & 7, qb = (id >> 3) & 15, kb = id >> 7;
  int tid = threadIdx.x, w = tid >> 6, lane = tid & 63;
  int wq = w >> 1, wk = w & 1;
  const unsigned short* Qb =
      Qf + ((size_t)(b * 32 + qb * 2 + wq) * 48) * 512 + (size_t)lane * 8;
  const unsigned short* Kb =
      Kf + ((size_t)(b * 32 + kb * 2 + wk) * 48) * 512 + (size_t)lane * 8;

  f32x16 acc[8];
#pragma unroll
  for (int h = 0; h < 8; h++) acc[h] = 0;
#pragma unroll
  for (int h = 0; h < 8; h++) {
#pragma unroll
    for (int t = 0; t < 6; t++) {
      bf16x8 a = *(const bf16x8*)(Qb + (size_t)(h * 6 + t) * 512);
      bf16x8 bb = *(const bf16x8*)(Kb + (size_t)(h * 6 + t) * 512);
      acc[h] = __builtin_amdgcn_mfma_f32_32x32x16_bf16(a, bb, acc[h], 0, 0, 0);
    }
  }

  float awv[16];
#pragma unroll
  for (int reg = 0; reg < 16; reg++) {
    int row = (reg & 3) + 8 * (reg >> 2) + 4 * (lane >> 5);
    awv[reg] = aw[b * 1024 + qb * 64 + wq * 32 + row];
  }
  float partial[8];
#pragma unroll
  for (int h = 0; h < 8; h++) partial[h] = 0.f;
  const float C2 = 0.10206207261596577f * 1.4426950408889634f;  // /sqrt(96)*log2e
#pragma unroll
  for (int reg = 0; reg < 16; reg++) {
    float v[8];
    float ssum = 0.f;
#pragma unroll
    for (int h = 0; h < 8; h++) {
      float e = exp2f(acc[h][reg] * C2);  // no max-shift needed
      v[h] = e;
      ssum += e;
    }
    float g = awv[reg] * __builtin_amdgcn_rcpf(ssum);  // aw==0 for padded q
#pragma unroll
    for (int h = 0; h < 8; h++) partial[h] += v[h] * g;
  }
#pragma unroll
  for (int h = 0; h < 8; h++) {
    float v = partial[h];
    v += __shfl_xor(v, 32);
    partial[h] = v;
  }
  if (lane < 32) {
#pragma unroll
    for (int h = 0; h < 8; h++) pbuf[w * 256 + lane * 8 + h] = partial[h];
  }
  __syncthreads();
#pragma unroll
  for (int wk2 = 0; wk2 < 2; wk2++) {
    float s = pbuf[wk2 * 256 + tid] + pbuf[(2 + wk2) * 256 + tid];
    int kcol = tid >> 3, h = tid & 7;
    Ptp[(((size_t)qb * 8 + b) * 1024 + kb * 64 + wk2 * 32 + kcol) * 8 + h] = s;
  }
}

// ---------------------------------------------------------------------------
// K5: out[b,o] = sum_k (sum_qb Ptp[qb][b][k][o&7]) * V[b,k,o]   (V bf16)
// grid (32 kc, 8 b); threads 0..191 each own 4 consecutive o (ushort4 loads)
// ---------------------------------------------------------------------------
__global__ __launch_bounds__(256) void finalize(
    const float* __restrict__ Ptp, const unsigned short* __restrict__ Vbf,
    float* __restrict__ out) {
  __shared__ float ps[256];  // 32 k x 8 h
  int kc = blockIdx.x, b = blockIdx.y;
  int t = threadIdx.x;
  {
    int k = kc * 32 + (t >> 3), h = t & 7;
    float s = 0.f;
#pragma unroll
    for (int qc = 0; qc < 16; qc++)
      s += Ptp[(((size_t)qc * 8 + b) * 1024 + k) * 8 + h];
    ps[t] = s;
  }
  __syncthreads();
  if (t < 192) {
    int o0 = t * 4;
    int hb = o0 & 7;  // 0 or 4
    float a0 = 0, a1 = 0, a2 = 0, a3 = 0;
    const unsigned short* Vb = Vbf + ((size_t)b * 1024 + kc * 32) * 768 + o0;
#pragma unroll 4
    for (int kk = 0; kk < 32; kk++) {
      ushort4 vv = *(const ushort4*)(Vb + (size_t)kk * 768);
      const float* p = &ps[kk * 8 + hb];
      a0 += p[0] * bf2f(vv.x);
      a1 += p[1] * bf2f(vv.y);
      a2 += p[2] * bf2f(vv.z);
      a3 += p[3] * bf2f(vv.w);
    }
    atomicAdd(&out[b * 768 + o0], a0);
    atomicAdd(&out[b * 768 + o0 + 1], a1);
    atomicAdd(&out[b * 768 + o0 + 2], a2);
    atomicAdd(&out[b * 768 + o0 + 3], a3);
  }
}

// ---------------------------------------------------------------------------
extern "C" void kernel_launch(void* const* d_in, const int* in_sizes, int n_in,
                              void* d_out, int out_size, void* d_ws,
                              size_t ws_size, hipStream_t stream) {
  const float* emb = (const float*)d_in[0];
  const int* tags = (const int*)d_in[1];
  const float* ww = (const float*)d_in[2];
  const float* wq = (const float*)d_in[3];
  const float* wk = (const float*)d_in[4];
  const float* wv = (const float*)d_in[5];
  float* out = (float*)d_out;
  char* ws = (char*)d_ws;
  unsigned short* Af  = (unsigned short*)(ws + 0);             // 12,582,912
  unsigned short* Wf  = (unsigned short*)(ws + 12582912);      //  3,538,944
  unsigned short* Qf  = (unsigned short*)(ws + 16121856);      // 12,582,912
  unsigned short* Kf  = (unsigned short*)(ws + 28704768);      // 12,582,912
  unsigned short* Vbf = (unsigned short*)(ws + 41287680);      // 12,582,912
  float* logits       = (float*)(ws + 53870592);               //     32,768
  float* aw           = (float*)(ws + 53903360);               //     32,768
  float* Ptp          = (float*)(ws + 53936128);               //  4,194,304

  hipMemsetAsync(out, 0, 8 * 768 * sizeof(float), stream);
  cast_inputs<<<2624, 384, 0, stream>>>(emb, tags, ww, wq, wk, wv, Af, logits,
                                        Wf);
  softmax_aw<<<8, 256, 0, stream>>>(logits, aw);
  qkv_gemm<<<dim3(64, 6, 3), 256, 0, stream>>>(Af, Wf, Qf, Kf, Vbf);
  attn<<<2048, 256, 0, stream>>>(Qf, Kf, aw, Ptp);
  finalize<<<dim3(32, 8), 256, 0, stream>>>(Ptp, Vbf, out);
}